// Round 1
// baseline (236.844 us; speedup 1.0000x reference)
//
#include <hip/hip_runtime.h>

// Problem constants (from reference)
static constexpr int kB = 2, kS = 2048, kD = 1024, kFF = 4096;
static constexpr int kM = kB * kS;  // 4096 token rows

typedef __attribute__((ext_vector_type(8))) short short8;
typedef __attribute__((ext_vector_type(4))) float f32x4;

__device__ __forceinline__ unsigned short f2bf(float f) {
  union { float f; unsigned int u; } c; c.f = f;
  unsigned int u = c.u;
  unsigned int r = u + 0x7FFFu + ((u >> 16) & 1u);  // RNE
  return (unsigned short)(r >> 16);
}

__device__ __forceinline__ void gload_lds16(const void* g, void* l) {
  __builtin_amdgcn_global_load_lds(
      (const __attribute__((address_space(1))) void*)g,
      (__attribute__((address_space(3))) void*)l, 16, 0, 0);
}

// ---------------- cast fp32 -> bf16 (vectorized) ----------------
__global__ __launch_bounds__(256) void cast_bf16_kernel(
    const float* __restrict__ in, unsigned short* __restrict__ out, int n) {
  int i = (blockIdx.x * 256 + threadIdx.x) * 4;
  if (i >= n) return;
  float4 v = *(const float4*)(in + i);
  ushort4 o;
  o.x = f2bf(v.x); o.y = f2bf(v.y); o.z = f2bf(v.z); o.w = f2bf(v.w);
  *(ushort4*)(out + i) = o;
}

// ------------- cast + transpose: W[K][N] fp32 -> Wt[N][K] bf16 (× scale) -------------
__global__ __launch_bounds__(1024) void cast_transpose_kernel(
    const float* __restrict__ W, unsigned short* __restrict__ Wt,
    int K, int N, float scale) {
  __shared__ float tile[32][33];
  int nb = blockIdx.x * 32, kb = blockIdx.y * 32;
  int tx = threadIdx.x, ty = threadIdx.y;
  tile[ty][tx] = W[(size_t)(kb + ty) * N + (nb + tx)];
  __syncthreads();
  Wt[(size_t)(nb + ty) * K + (kb + tx)] = f2bf(tile[tx][ty] * scale);
}

// ---------------- GEMM: C[M,N] = A[M,K] @ Bt[N,K]^T + bias (opt relu) ----------------
// 128x128 tile, BK=64, 4 waves (2x2), each wave 64x64 via 4x4 of 16x16x32 MFMA.
template <int OUT_BF16, int RELU>
__global__ __launch_bounds__(256) void gemm_bt(
    const unsigned short* __restrict__ A, const unsigned short* __restrict__ Bt,
    const float* __restrict__ bias, void* __restrict__ Cout,
    int M, int N, int K) {
  __shared__ __align__(16) unsigned short sA[128 * 64];
  __shared__ __align__(16) unsigned short sB[128 * 64];
  const int tid = threadIdx.x;
  const int wave = tid >> 6, lane = tid & 63;
  const int wr = wave >> 1, wc = wave & 1;
  const int m0 = blockIdx.y * 128, n0 = blockIdx.x * 128;
  const int srow = lane >> 3, scol = (lane & 7) * 8;

  f32x4 acc[4][4] = {};

  for (int k0 = 0; k0 < K; k0 += 64) {
#pragma unroll
    for (int i = 0; i < 4; ++i) {
      const int chunk = i * 4 + wave;               // 16 chunks of 8 rows
      const int r = chunk * 8 + srow;
      gload_lds16(A + (size_t)(m0 + r) * K + (k0 + scol), &sA[chunk * 512]);
      gload_lds16(Bt + (size_t)(n0 + r) * K + (k0 + scol), &sB[chunk * 512]);
    }
    __syncthreads();
#pragma unroll
    for (int kk = 0; kk < 64; kk += 32) {
      const int kcol = kk + (lane >> 4) * 8;
      short8 af[4], bfr[4];
#pragma unroll
      for (int m = 0; m < 4; ++m)
        af[m] = *(const short8*)&sA[(wr * 64 + m * 16 + (lane & 15)) * 64 + kcol];
#pragma unroll
      for (int n = 0; n < 4; ++n)
        bfr[n] = *(const short8*)&sB[(wc * 64 + n * 16 + (lane & 15)) * 64 + kcol];
#pragma unroll
      for (int m = 0; m < 4; ++m)
#pragma unroll
        for (int n = 0; n < 4; ++n)
          acc[m][n] = __builtin_amdgcn_mfma_f32_16x16x32_bf16(af[m], bfr[n], acc[m][n], 0, 0, 0);
    }
    __syncthreads();
  }

  const int cl = lane & 15, rg = lane >> 4;
#pragma unroll
  for (int n = 0; n < 4; ++n) {
    const int col = n0 + wc * 64 + n * 16 + cl;
    const float bias_v = bias[col];
#pragma unroll
    for (int m = 0; m < 4; ++m) {
      const int rbase = m0 + wr * 64 + m * 16 + rg * 4;
#pragma unroll
      for (int j = 0; j < 4; ++j) {
        float v = acc[m][n][j] + bias_v;
        if (RELU) v = fmaxf(v, 0.0f);
        if (OUT_BF16)
          ((unsigned short*)Cout)[(size_t)(rbase + j) * N + col] = f2bf(v);
        else
          ((float*)Cout)[(size_t)(rbase + j) * N + col] = v;
      }
    }
  }
}

// -------- fused residual + LayerNorm over D=1024: H = LN(X + Y) * g + b --------
// One block (256 thr) per row; writes fp32 H and optionally bf16 H.
__global__ __launch_bounds__(256) void ln_res_kernel(
    const float* __restrict__ X, const float* Y,
    const float* __restrict__ gg, const float* __restrict__ bb,
    float* Hf, unsigned short* Hb) {
  const int row = blockIdx.x, t = threadIdx.x;
  const size_t base = (size_t)row * 1024 + t * 4;
  float4 xv = *(const float4*)(X + base);
  float4 yv = *(const float4*)(Y + base);
  float a0 = xv.x + yv.x, a1 = xv.y + yv.y, a2 = xv.z + yv.z, a3 = xv.w + yv.w;
  float s = a0 + a1 + a2 + a3;
  float ss = a0 * a0 + a1 * a1 + a2 * a2 + a3 * a3;
#pragma unroll
  for (int off = 32; off > 0; off >>= 1) {
    s += __shfl_down(s, off);
    ss += __shfl_down(ss, off);
  }
  __shared__ float rs[4], rss[4];
  __shared__ float smean, srstd;
  const int wave = t >> 6, lane = t & 63;
  if (lane == 0) { rs[wave] = s; rss[wave] = ss; }
  __syncthreads();
  if (t == 0) {
    float S1 = rs[0] + rs[1] + rs[2] + rs[3];
    float S2 = rss[0] + rss[1] + rss[2] + rss[3];
    float mean = S1 * (1.0f / 1024.0f);
    float var = S2 * (1.0f / 1024.0f) - mean * mean;
    smean = mean;
    srstd = rsqrtf(var + 1e-5f);
  }
  __syncthreads();
  const float mean = smean, rstd = srstd;
  float4 gv = *(const float4*)(gg + t * 4);
  float4 bv = *(const float4*)(bb + t * 4);
  float o0 = (a0 - mean) * rstd * gv.x + bv.x;
  float o1 = (a1 - mean) * rstd * gv.y + bv.y;
  float o2 = (a2 - mean) * rstd * gv.z + bv.z;
  float o3 = (a3 - mean) * rstd * gv.w + bv.w;
  float4 ov; ov.x = o0; ov.y = o1; ov.z = o2; ov.w = o3;
  *(float4*)(Hf + base) = ov;
  if (Hb) {
    ushort4 hb;
    hb.x = f2bf(o0); hb.y = f2bf(o1); hb.z = f2bf(o2); hb.w = f2bf(o3);
    *(ushort4*)(Hb + base) = hb;
  }
}

// ---------------------------------------------------------------------------
// att = s_bh * v where s_bh == S exactly (softmax over q sums to 1 per (b,h,k),
// then summed over k -> S). So: out = LN(h1 + FFN(h1)), h1 = LN(z + 2048*(z@Wv+bv)@Wo + bo).
// q/k/mask are dead.
// ---------------------------------------------------------------------------
extern "C" void kernel_launch(void* const* d_in, const int* in_sizes, int n_in,
                              void* d_out, int out_size, void* d_ws, size_t ws_size,
                              hipStream_t stream) {
  const float* z  = (const float*)d_in[2];
  const float* Wv = (const float*)d_in[8];
  const float* bv = (const float*)d_in[9];
  const float* Wo = (const float*)d_in[10];
  const float* bo = (const float*)d_in[11];
  const float* W1 = (const float*)d_in[12];
  const float* b1 = (const float*)d_in[13];
  const float* W2 = (const float*)d_in[14];
  const float* b2 = (const float*)d_in[15];
  const float* lng = (const float*)d_in[16];
  const float* lnb = (const float*)d_in[17];
  float* out = (float*)d_out;

  char* ws = (char*)d_ws;
  // layout (bytes):
  //   [0,        8M)  zbf   (bf16 z)            -- dead after GEMM1
  //   [8M,      16M)  vbf / h1bf (bf16)         -- dead after GEMM3
  //   [0,       16M)  ff    (fp32)              -- written by GEMM4 (reuses the above)
  //   [16M,     24M)  wbf   (current weight^T bf16)
  //   [24M,     40M)  att / h1f (fp32)
  //   [40M,     72M)  a1    (bf16, post-relu)
  unsigned short* zbf = (unsigned short*)(ws + 0);
  unsigned short* vbf = (unsigned short*)(ws + 8388608);
  float*          ff  = (float*)(ws + 0);
  unsigned short* wbf = (unsigned short*)(ws + 16777216);
  float*          att = (float*)(ws + 25165824);
  unsigned short* a1  = (unsigned short*)(ws + 41943040);

  const int nZ = kM * kD;  // 4194304

  // z -> bf16
  cast_bf16_kernel<<<dim3(nZ / 1024), dim3(256), 0, stream>>>(z, zbf, nZ);

  // Wv^T bf16
  cast_transpose_kernel<<<dim3(kD / 32, kD / 32), dim3(32, 32), 0, stream>>>(
      Wv, wbf, kD, kD, 1.0f);
  // v = z @ Wv + bv   (bf16 out)
  gemm_bt<1, 0><<<dim3(kD / 128, kM / 128), dim3(256), 0, stream>>>(
      zbf, wbf, bv, vbf, kM, kD, kD);

  // (2048*Wo)^T bf16
  cast_transpose_kernel<<<dim3(kD / 32, kD / 32), dim3(32, 32), 0, stream>>>(
      Wo, wbf, kD, kD, (float)kS);
  // att = v @ (2048*Wo) + bo   (fp32 out)
  gemm_bt<0, 0><<<dim3(kD / 128, kM / 128), dim3(256), 0, stream>>>(
      vbf, wbf, bo, att, kM, kD, kD);

  // h1 = LN(z + att): fp32 into att (in place), bf16 into vbf slot
  ln_res_kernel<<<dim3(kM), dim3(256), 0, stream>>>(z, att, lng, lnb, att, vbf);

  // W1^T bf16 [FF][D]
  cast_transpose_kernel<<<dim3(kFF / 32, kD / 32), dim3(32, 32), 0, stream>>>(
      W1, wbf, kD, kFF, 1.0f);
  // a1 = relu(h1 @ W1 + b1)   (bf16 out)
  gemm_bt<1, 1><<<dim3(kFF / 128, kM / 128), dim3(256), 0, stream>>>(
      vbf, wbf, b1, a1, kM, kFF, kD);

  // W2^T bf16 [D][FF]
  cast_transpose_kernel<<<dim3(kD / 32, kFF / 32), dim3(32, 32), 0, stream>>>(
      W2, wbf, kFF, kD, 1.0f);
  // ff = a1 @ W2 + b2   (fp32 out)
  gemm_bt<0, 0><<<dim3(kD / 128, kM / 128), dim3(256), 0, stream>>>(
      a1, wbf, b2, ff, kM, kD, kFF);

  // out = LN(h1 + ff)
  ln_res_kernel<<<dim3(kM), dim3(256), 0, stream>>>(att, ff, lng, lnb, out, nullptr);
}